// Round 10
// baseline (301.451 us; speedup 1.0000x reference)
//
#include <hip/hip_runtime.h>
#include <cstdint>
#include <cstddef>

// ---------------------------------------------------------------------------
// Problem constants
// ---------------------------------------------------------------------------
#define BB    8      // batch
#define NH    12     // heads
#define BH    96     // BB*NH
#define SS    1024   // image tokens (32x32)
#define QQ    2048   // text tokens
#define DD    64     // head dim
#define HID   768
#define EDGE  32
#define KPOOL 16
#define POOLED 17

typedef short bf16x8 __attribute__((ext_vector_type(8)));
typedef _Float16 f16x8 __attribute__((ext_vector_type(8)));
typedef float f32x4  __attribute__((ext_vector_type(4)));

#define MFMA16B(a, b, c) __builtin_amdgcn_mfma_f32_16x16x32_bf16((a), (b), (c), 0, 0, 0)
#define MFMA16H(a, b, c) __builtin_amdgcn_mfma_f32_16x16x32_f16((a), (b), (c), 0, 0, 0)

// scores in base-2: Q pre-scaled by log2(e)/8 so exp(s/8) == exp2(score2)
#define QSCALE 0.18033688011112042f

#if __has_builtin(__builtin_amdgcn_exp2f)
#define EXP2(x) __builtin_amdgcn_exp2f(x)
#else
#define EXP2(x) exp2f(x)
#endif

__device__ __forceinline__ short f2bf(float x) {
    unsigned u = __builtin_bit_cast(unsigned, x);
    u = u + 0x7fffu + ((u >> 16) & 1u);          // RNE
    return (short)(u >> 16);
}
__device__ __forceinline__ f16x8 ash(bf16x8 v) {
    return __builtin_bit_cast(f16x8, v);
}

// Fragment-order address for a [rows][K=768] bf16 matrix, 32-k chunks:
// addr(row,k) = ((row>>4)*24 + (k>>5))*512 + ((k>>3)&3)*128 + (row&15)*8 + (k&7)
__device__ __forceinline__ size_t fragaddr(int row, int k) {
    return ((size_t)(row >> 4) * 24 + (k >> 5)) * 512 + ((k >> 3) & 3) * 128
         + (row & 15) * 8 + (k & 7);
}

// ---------------------------------------------------------------------------
// Fragment-order layout for Qs/Ks:
//   rows grouped by 16 (group g, row-in-group c). Per group: 2048 shorts =
//   4 chunks of 512: ch0=hi,k[0:32) ch1=hi,k[32:64) (ch2/ch3 unused)
//   chunk internal: [quad(4)][c(16)][j(8)]  -> frag read = base + lane*8 shorts
// Both Q and K: fp16 hi plane ONLY (single-plane scores; noise ~6e-4, 8x
// below the r1 bf16 failure point; P and L share identical scores so the
// softmax normalization is exact under the perturbation).
// ---------------------------------------------------------------------------

// K0a: cast text -> Qs fragment-order (scaled by QSCALE), fp16 hi plane only
__global__ __launch_bounds__(256) void k_castq(const float* __restrict__ txt,
                                               short* __restrict__ Qs) {
    int i = blockIdx.x * 256 + threadIdx.x;
    int quad = i & 3, kh = (i >> 2) & 1;
    int row = i >> 3;                    // bh*2048 + q
    int c = row & 15, g = row >> 4;
    int q = row & 2047, bh = row >> 11;
    int b = bh / NH, h = bh - b * NH;
    const float* sp = txt + ((size_t)b * QQ + q) * HID + h * DD + kh * 32 + quad * 8;
    bf16x8 vh;
#pragma unroll
    for (int j = 0; j < 8; j++) {
        _Float16 hi = (_Float16)(sp[j] * QSCALE);
        vh[j] = __builtin_bit_cast(short, hi);
    }
    *(bf16x8*)(Qs + (size_t)g * 2048 + kh * 512 + quad * 128 + c * 8) = vh;
}

// K0b: cast image -> Ks fragment-order (unscaled), fp16 hi plane ONLY
__global__ __launch_bounds__(256) void k_castk(const float* __restrict__ img,
                                               short* __restrict__ Ks) {
    int i = blockIdx.x * 256 + threadIdx.x;
    int quad = i & 3, kh = (i >> 2) & 1;
    int row = i >> 3;                    // bh*1024 + s
    int c = row & 15, g = row >> 4;
    int s = row & 1023, bh = row >> 10;
    int b = bh / NH, h = bh - b * NH;
    const float* sp = img + ((size_t)b * SS + s) * HID + h * DD + kh * 32 + quad * 8;
    bf16x8 vh;
#pragma unroll
    for (int j = 0; j < 8; j++) {
        _Float16 hi = (_Float16)sp[j];
        vh[j] = __builtin_bit_cast(short, hi);
    }
    *(bf16x8*)(Ks + (size_t)g * 2048 + kh * 512 + quad * 128 + c * 8) = vh;
}

// K0c: blocks 0..143: W_in [k][n] -> bf16 Wt in FRAGMENT order [n-row][k].
//      block 144: W_up [64][256] -> bf16 B-fragment order Wupb.
__global__ __launch_bounds__(256) void k_castw(const float* __restrict__ W,
                                               const float* __restrict__ Wup,
                                               short* __restrict__ Wt,
                                               short* __restrict__ Wupb) {
    if (blockIdx.x == 144) {
        for (int i = threadIdx.x; i < 16384; i += 256) {
            int k = i >> 8, n = i & 255;
            int addr = (n >> 4) * 1024 + (k >> 5) * 512 + ((k >> 3) & 3) * 128
                     + (n & 15) * 8 + (k & 7);
            Wupb[addr] = f2bf(Wup[k * 256 + n]);
        }
        return;
    }
    __shared__ float T[64][65];
    int bx = blockIdx.x % 12, by = blockIdx.x / 12;
    for (int i = threadIdx.x; i < 4096; i += 256) {
        int r = i >> 6, cc = i & 63;
        T[r][cc] = W[(size_t)(by * 64 + r) * HID + bx * 64 + cc];
    }
    __syncthreads();
    for (int i = threadIdx.x; i < 4096; i += 256) {
        int r = i >> 6, cc = i & 63;
        int n = bx * 64 + r, k = by * 64 + cc;
        Wt[fragaddr(n, k)] = f2bf(T[cc][r]);
    }
}

// ---------------------------------------------------------------------------
// K1+K2 FUSED, 128 q per block (4 x 32-q iterations).
// r9 lesson: 32-q blocks made the kernel traffic-bound (86 MB: 50 MB atomic
// RMW + K L2 replication) at ~900 GB/s effective. This version: grid 1536
// (96 bh x 16 qb), each block iterates 4 q-subtiles, accumulates iattn
// contributions in LDS (same-thread +=, no race), single atomicAdd pass at
// the end. Atomic traffic /4, K reuse x4. Inner body identical to r9 (pt[16]
// regs reused across iterations; all indices static).
// ---------------------------------------------------------------------------
__global__ __launch_bounds__(512) void k_fused(const short* __restrict__ Qs,
                                               const short* __restrict__ Ks,
                                               float* __restrict__ iattn) {
    __shared__ short Kt[2][4096];        // 16 KB: chunk = 64 s x 64 k fp16
    __shared__ float iacc[2][1024];      // 8 KB: per-qi-half block-local iattn
    __shared__ float Lred[2][4][16];     // cross-si L partials

    int bh = blockIdx.x >> 4, qb = blockIdx.x & 15;
    int tid = threadIdx.x;
    int w = tid >> 6, lane = tid & 63;
    int qi = w >> 2, si = w & 3;
    int quad = lane >> 4, c = lane & 15;

    for (int i = tid; i < 2048; i += 512) ((float*)iacc)[i] = 0.f;

    const short* kbase = Ks + (size_t)bh * SS * 128;
    size_t soff = (size_t)(tid >> 7) * 2048 + (size_t)(tid & 127) * 8;

    f32x4 pt[16];

#pragma unroll 1
    for (int qq = 0; qq < 4; qq++) {
        // Q fragments (single-plane): group = bh*128 + (qb*4+qq)*2 + qi
        const short* ap = Qs + ((size_t)bh * 128 + (qb * 4 + qq) * 2 + qi) * 2048
                        + lane * 8;
        f16x8 a0 = ash(*(const bf16x8*)(ap));
        f16x8 a1 = ash(*(const bf16x8*)(ap + 512));

        bf16x8 st = *(const bf16x8*)(kbase + soff);

#pragma unroll
        for (int cc = 0; cc < 16; cc++) {
            int buf = cc & 1;
            *(bf16x8*)(&Kt[buf][tid * 8]) = st;
            if (cc + 1 < 16)
                st = *(const bf16x8*)(kbase + (size_t)(cc + 1) * 8192 + soff);
            __syncthreads();
            f16x8 kb0 = ash(*(const bf16x8*)(&Kt[buf][si * 1024 + lane * 8]));
            f16x8 kb1 = ash(*(const bf16x8*)(&Kt[buf][si * 1024 + 512 + lane * 8]));
            f32x4 acc = (f32x4){0.f, 0.f, 0.f, 0.f};
            acc = MFMA16H(a0, kb0, acc);
            acc = MFMA16H(a1, kb1, acc);
#pragma unroll
            for (int r = 0; r < 4; r++) pt[cc][r] = EXP2(acc[r]);
        }

        // ---- L_q: register sum over chunks, shfl over c, LDS over si ----
        float rl[4];
#pragma unroll
        for (int r = 0; r < 4; r++) {
            float v = 0.f;
#pragma unroll
            for (int cc = 0; cc < 16; cc++) v += pt[cc][r];
            v += __shfl_xor(v, 1);
            v += __shfl_xor(v, 2);
            v += __shfl_xor(v, 4);
            v += __shfl_xor(v, 8);
            if (c == 0) Lred[qi][si][quad * 4 + r] = v;
        }
        __syncthreads();
#pragma unroll
        for (int r = 0; r < 4; r++)
            rl[r] = __builtin_amdgcn_rcpf(
                Lred[qi][0][quad * 4 + r] + Lred[qi][1][quad * 4 + r] +
                Lred[qi][2][quad * 4 + r] + Lred[qi][3][quad * 4 + r]);

        // ---- accumulate P/L into block-local iacc (same-thread +=) ----
#pragma unroll
        for (int cc = 0; cc < 16; cc++) {
            float v = pt[cc][0] * rl[0] + pt[cc][1] * rl[1]
                    + pt[cc][2] * rl[2] + pt[cc][3] * rl[3];
            v += __shfl_xor(v, 16);
            v += __shfl_xor(v, 32);
            if (lane < 16) iacc[qi][cc * 64 + si * 16 + lane] += v;
        }
        __syncthreads();                 // WAR: Lred/iacc settled before next iter
    }

    for (int i = tid; i < 1024; i += 512)
        atomicAdd(&iattn[(size_t)bh * SS + i], iacc[0][i] + iacc[1][i]);
}

// ---------------------------------------------------------------------------
// K4: fused pool+argmax+region-gather+upsample GEMM + pixel-shuffle.
// Xb written in FRAGMENT order (A-operand of k_out).
// ---------------------------------------------------------------------------
__global__ __launch_bounds__(256, 2) void k_up(const float* __restrict__ img,
                                               const float* __restrict__ iattn,
                                               const short* __restrict__ Wupb,
                                               short* __restrict__ Xb) {
    __shared__ short Reg[16384];         // 32 KB, aliased for pool phase
    float* F = (float*)Reg;
    float* Apool = F;                    // [1024]
    float* Vp = F + 1024;                // [544]
    float* bvp = F + 1568;               // [256]
    int*   bip = (int*)(F + 1824);       // [256]

    int bh = blockIdx.x >> 2, nq = blockIdx.x & 3;
    int b = bh / NH, h = bh - b * NH;
    int tid = threadIdx.x;
    int w = tid >> 6, lane = tid & 63;
    int quad = lane >> 4, c = lane & 15;

    // ---- pool + argmax (np first-max tiebreak) ----
    for (int i = tid; i < 1024; i += 256) Apool[i] = iattn[(size_t)bh * SS + i];
    __syncthreads();
    for (int i = tid; i < POOLED * EDGE; i += 256) {
        int r = i >> 5, cc = i & 31;
        float s = 0.f;
#pragma unroll
        for (int k = 0; k < KPOOL; k++) s += Apool[(r + k) * EDGE + cc];
        Vp[i] = s;
    }
    __syncthreads();
    float best = -1e30f;
    int bidx = 1 << 30;
    for (int i = tid; i < POOLED * POOLED; i += 256) {
        int r = i / POOLED, cc = i - r * POOLED;
        float s = 0.f;
#pragma unroll
        for (int k = 0; k < KPOOL; k++) s += Vp[r * EDGE + cc + k];
        if (s > best || (s == best && i < bidx)) { best = s; bidx = i; }
    }
    bvp[tid] = best;
    bip[tid] = bidx;
    __syncthreads();
    for (int off = 128; off; off >>= 1) {
        if (tid < off) {
            float ov = bvp[tid + off];
            int oi = bip[tid + off];
            if (ov > bvp[tid] || (ov == bvp[tid] && oi < bip[tid])) {
                bvp[tid] = ov;
                bip[tid] = oi;
            }
        }
        __syncthreads();
    }
    int widx = bip[0];
    __syncthreads();                     // all reads done before staging overwrites
    int r0 = widx / POOLED, c0 = widx - r0 * POOLED;

    // ---- stage region bf16 in A-fragment order ----
    for (int p = tid; p < 2048; p += 256) {
        int pos = p >> 3, sub = p & 7;   // sub -> d = sub*8..sub*8+7
        int gi = r0 + (pos >> 4), gj = c0 + (pos & 15);
        const float* sp = img + ((size_t)b * SS + gi * EDGE + gj) * HID + h * DD + sub * 8;
        bf16x8 v;
#pragma unroll
        for (int j = 0; j < 8; j++) v[j] = f2bf(sp[j]);
        *(bf16x8*)(&Reg[(pos >> 4) * 1024 + (sub >> 2) * 512 + (sub & 3) * 128 + (pos & 15) * 8]) = v;
    }
    __syncthreads();

    // ---- B-fragments (this block's 64 oc = 4 n-tiles) ----
    bf16x8 bu[4][2];
#pragma unroll
    for (int u = 0; u < 4; u++) {
#pragma unroll
        for (int kh = 0; kh < 2; kh++)
            bu[u][kh] = *(const bf16x8*)(Wupb + (nq * 4 + u) * 1024 + kh * 512 + lane * 8);
    }

    // ---- MFMA + pixel-shuffle epilogue (fragment-order Xb writes) ----
#pragma unroll
    for (int t = 0; t < 4; t++) {
        int g = w * 4 + t;               // pos group [0,16)
        bf16x8 a0 = *(const bf16x8*)(&Reg[g * 1024 + lane * 8]);
        bf16x8 a1 = *(const bf16x8*)(&Reg[g * 1024 + 512 + lane * 8]);
#pragma unroll
        for (int u = 0; u < 4; u++) {
            f32x4 acc = (f32x4){0.f, 0.f, 0.f, 0.f};
            acc = MFMA16B(a0, bu[u][0], acc);
            acc = MFMA16B(a1, bu[u][1], acc);
#pragma unroll
            for (int r = 0; r < 4; r++) {
                int pos = g * 16 + quad * 4 + r;
                int oc = nq * 64 + u * 16 + c;
                int i16 = pos >> 4, j16 = pos & 15;
                int a = oc >> 7, bbit = (oc >> 6) & 1, dp = oc & 63;
                int p2 = (2 * i16 + a) * EDGE + (2 * j16 + bbit);
                int row = b * SS + p2, kdim = h * DD + dp;
                Xb[fragaddr(row, kdim)] = f2bf(acc[r]);
            }
        }
    }
}

// ---------------------------------------------------------------------------
// K5: out = img + gelu(X @ W_in)   (bf16 MFMA, M=8192 N=768 K=768)
// LDS-staged from fragment-order Xb/Wt (proven r8 structure).
// ---------------------------------------------------------------------------
__global__ __launch_bounds__(256) void k_out(const short* __restrict__ Xb,
                                             const short* __restrict__ Wt,
                                             const float* __restrict__ img,
                                             float* __restrict__ out) {
    __shared__ short At[2][4096];        // 128 rows x 32 k, frag order (16 KB)
    __shared__ short Bt[2][2048];        // 64 rows x 32 k, frag order (8 KB)
    int mblk = blockIdx.x & 63, nblk = blockIdx.x >> 6;
    int tid = threadIdx.x;
    int w = tid >> 6, lane = tid & 63;
    int quad = lane >> 4, c = lane & 15;
    int gm0 = mblk * 8, gn0 = nblk * 4;  // 16-row group bases
    int m0 = mblk * 128, n0 = nblk * 64;

    // staging sources (unit = 16B): A units tid and tid+256, B unit tid
    int ua1 = tid + 256;
    const short* srcA0 = Xb + ((size_t)(gm0 + (tid >> 6)) * 24) * 512 + (tid & 63) * 8;
    const short* srcA1 = Xb + ((size_t)(gm0 + (ua1 >> 6)) * 24) * 512 + (ua1 & 63) * 8;
    const short* srcB  = Wt + ((size_t)(gn0 + (tid >> 6)) * 24) * 512 + (tid & 63) * 8;

    f32x4 acc[2][4];
#pragma unroll
    for (int t = 0; t < 2; t++)
#pragma unroll
        for (int u = 0; u < 4; u++) acc[t][u] = (f32x4){0.f, 0.f, 0.f, 0.f};

    bf16x8 sa0 = *(const bf16x8*)(srcA0);
    bf16x8 sa1 = *(const bf16x8*)(srcA1);
    bf16x8 sb  = *(const bf16x8*)(srcB);

    for (int kk = 0; kk < 24; kk++) {
        int buf = kk & 1;
        *(bf16x8*)(&At[buf][tid * 8]) = sa0;
        *(bf16x8*)(&At[buf][ua1 * 8]) = sa1;
        *(bf16x8*)(&Bt[buf][tid * 8]) = sb;
        if (kk + 1 < 24) {
            sa0 = *(const bf16x8*)(srcA0 + (kk + 1) * 512);
            sa1 = *(const bf16x8*)(srcA1 + (kk + 1) * 512);
            sb  = *(const bf16x8*)(srcB  + (kk + 1) * 512);
        }
        __syncthreads();
        bf16x8 a0 = *(const bf16x8*)(&At[buf][(2 * w + 0) * 512 + lane * 8]);
        bf16x8 a1 = *(const bf16x8*)(&At[buf][(2 * w + 1) * 512 + lane * 8]);
        bf16x8 b0 = *(const bf16x8*)(&Bt[buf][0 * 512 + lane * 8]);
        bf16x8 b1 = *(const bf16x8*)(&Bt[buf][1 * 512 + lane * 8]);
        bf16x8 b2 = *(const bf16x8*)(&Bt[buf][2 * 512 + lane * 8]);
        bf16x8 b3 = *(const bf16x8*)(&Bt[buf][3 * 512 + lane * 8]);
        acc[0][0] = MFMA16B(a0, b0, acc[0][0]);
        acc[0][1] = MFMA16B(a0, b1, acc[0][1]);
        acc[0][2] = MFMA16B(a0, b2, acc[0][2]);
        acc[0][3] = MFMA16B(a0, b3, acc[0][3]);
        acc[1][0] = MFMA16B(a1, b0, acc[1][0]);
        acc[1][1] = MFMA16B(a1, b1, acc[1][1]);
        acc[1][2] = MFMA16B(a1, b2, acc[1][2]);
        acc[1][3] = MFMA16B(a1, b3, acc[1][3]);
    }

#pragma unroll
    for (int t = 0; t < 2; t++) {
#pragma unroll
        for (int u = 0; u < 4; u++) {
#pragma unroll
            for (int r = 0; r < 4; r++) {
                int row = m0 + w * 32 + t * 16 + quad * 4 + r;
                int col = n0 + u * 16 + c;
                float x = acc[t][u][r];
                float g = 0.5f * x * (1.f + erff(x * 0.70710678118654752f));
                size_t o = (size_t)row * HID + col;
                out[o] = img[o] + g;
            }
        }
    }
}

// ---------------------------------------------------------------------------
// launch
// ---------------------------------------------------------------------------
extern "C" void kernel_launch(void* const* d_in, const int* in_sizes, int n_in,
                              void* d_out, int out_size, void* d_ws, size_t ws_size,
                              hipStream_t stream) {
    const float* img = (const float*)d_in[0];   // [8,1024,768]
    const float* txt = (const float*)d_in[1];   // [8,2048,768]
    const float* Win = (const float*)d_in[2];   // [768,768]
    const float* Wup = (const float*)d_in[3];   // [64,256]
    float* out = (float*)d_out;

    char* w = (char*)d_ws;
    short* Qs    = (short*)(w);                         // 96*2048*128*2 = 50331648
    short* Ks    = (short*)(w + 50331648);              // 96*1024*128*2 = 25165824
    short* Wt    = (short*)(w + 75497472);              // 768*768*2     = 1179648
    float* iattn = (float*)(w + 77463552);              // 96*1024*4     = 393216
    short* Wupb  = (short*)(w + 77856768);              // 16384*2       = 32768
    short* Xb    = (short*)(w);                         // aliases Qs (dead after k_fused)

    k_castq<<<dim3(6144), dim3(256), 0, stream>>>(txt, Qs);
    k_castk<<<dim3(3072), dim3(256), 0, stream>>>(img, Ks);
    k_castw<<<dim3(145), dim3(256), 0, stream>>>(Win, Wup, Wt, Wupb);
    hipMemsetAsync(iattn, 0, (size_t)BH * SS * sizeof(float), stream);
    k_fused<<<dim3(1536), dim3(512), 0, stream>>>(Qs, Ks, iattn);
    k_up<<<dim3(384), dim3(256), 0, stream>>>(img, iattn, Wupb, Xb);
    k_out<<<dim3(768), dim3(256), 0, stream>>>(Xb, Wt, img, out);
}

// Round 11
// 265.991 us; speedup vs baseline: 1.1333x; 1.1333x over previous
//
#include <hip/hip_runtime.h>
#include <cstdint>
#include <cstddef>

// ---------------------------------------------------------------------------
// Problem constants
// ---------------------------------------------------------------------------
#define BB    8      // batch
#define NH    12     // heads
#define BH    96     // BB*NH
#define SS    1024   // image tokens (32x32)
#define QQ    2048   // text tokens
#define DD    64     // head dim
#define HID   768
#define EDGE  32
#define KPOOL 16
#define POOLED 17

typedef short bf16x8 __attribute__((ext_vector_type(8)));
typedef _Float16 f16x8 __attribute__((ext_vector_type(8)));
typedef float f32x4  __attribute__((ext_vector_type(4)));

#define MFMA16B(a, b, c) __builtin_amdgcn_mfma_f32_16x16x32_bf16((a), (b), (c), 0, 0, 0)
#define MFMA16H(a, b, c) __builtin_amdgcn_mfma_f32_16x16x32_f16((a), (b), (c), 0, 0, 0)

// scores in base-2: Q pre-scaled by log2(e)/8 so exp(s/8) == exp2(score2)
#define QSCALE 0.18033688011112042f

#if __has_builtin(__builtin_amdgcn_exp2f)
#define EXP2(x) __builtin_amdgcn_exp2f(x)
#else
#define EXP2(x) exp2f(x)
#endif

__device__ __forceinline__ short f2bf(float x) {
    unsigned u = __builtin_bit_cast(unsigned, x);
    u = u + 0x7fffu + ((u >> 16) & 1u);          // RNE
    return (short)(u >> 16);
}
__device__ __forceinline__ f16x8 ash(bf16x8 v) {
    return __builtin_bit_cast(f16x8, v);
}

// Fragment-order address for a [rows][K=768] bf16 matrix, 32-k chunks:
// addr(row,k) = ((row>>4)*24 + (k>>5))*512 + ((k>>3)&3)*128 + (row&15)*8 + (k&7)
__device__ __forceinline__ size_t fragaddr(int row, int k) {
    return ((size_t)(row >> 4) * 24 + (k >> 5)) * 512 + ((k >> 3) & 3) * 128
         + (row & 15) * 8 + (k & 7);
}

// Partials live in the DEAD lo-half of each Qs group (Q is single-plane):
// float j -> float-index (j>>9)*1024 + 512 + (j&511) in the float view of Qs.
__device__ __forceinline__ size_t partaddr(size_t j) {
    return (j >> 9) * 1024 + 512 + (j & 511);
}

// ---------------------------------------------------------------------------
// Fragment-order layout for Qs/Ks:
//   rows grouped by 16 (group g, row-in-group c). Per group: 2048 shorts =
//   4 chunks of 512: ch0=hi,k[0:32) ch1=hi,k[32:64) (ch2/ch3 = partials space)
//   chunk internal: [quad(4)][c(16)][j(8)]  -> frag read = base + lane*8 shorts
// Both Q and K: fp16 hi plane ONLY (single-plane scores; noise ~6e-4, 8x
// below the r1 bf16 failure point; P and L share identical scores so the
// softmax normalization is exact under the perturbation).
// ---------------------------------------------------------------------------

// K0a: cast text -> Qs fragment-order (scaled by QSCALE), fp16 hi plane only
__global__ __launch_bounds__(256) void k_castq(const float* __restrict__ txt,
                                               short* __restrict__ Qs) {
    int i = blockIdx.x * 256 + threadIdx.x;
    int quad = i & 3, kh = (i >> 2) & 1;
    int row = i >> 3;                    // bh*2048 + q
    int c = row & 15, g = row >> 4;
    int q = row & 2047, bh = row >> 11;
    int b = bh / NH, h = bh - b * NH;
    const float* sp = txt + ((size_t)b * QQ + q) * HID + h * DD + kh * 32 + quad * 8;
    bf16x8 vh;
#pragma unroll
    for (int j = 0; j < 8; j++) {
        _Float16 hi = (_Float16)(sp[j] * QSCALE);
        vh[j] = __builtin_bit_cast(short, hi);
    }
    *(bf16x8*)(Qs + (size_t)g * 2048 + kh * 512 + quad * 128 + c * 8) = vh;
}

// K0b: cast image -> Ks fragment-order (unscaled), fp16 hi plane ONLY
__global__ __launch_bounds__(256) void k_castk(const float* __restrict__ img,
                                               short* __restrict__ Ks) {
    int i = blockIdx.x * 256 + threadIdx.x;
    int quad = i & 3, kh = (i >> 2) & 1;
    int row = i >> 3;                    // bh*1024 + s
    int c = row & 15, g = row >> 4;
    int s = row & 1023, bh = row >> 10;
    int b = bh / NH, h = bh - b * NH;
    const float* sp = img + ((size_t)b * SS + s) * HID + h * DD + kh * 32 + quad * 8;
    bf16x8 vh;
#pragma unroll
    for (int j = 0; j < 8; j++) {
        _Float16 hi = (_Float16)sp[j];
        vh[j] = __builtin_bit_cast(short, hi);
    }
    *(bf16x8*)(Ks + (size_t)g * 2048 + kh * 512 + quad * 128 + c * 8) = vh;
}

// K0c: blocks 0..143: W_in [k][n] -> bf16 Wt in FRAGMENT order [n-row][k].
//      block 144: W_up [64][256] -> bf16 B-fragment order Wupb.
__global__ __launch_bounds__(256) void k_castw(const float* __restrict__ W,
                                               const float* __restrict__ Wup,
                                               short* __restrict__ Wt,
                                               short* __restrict__ Wupb) {
    if (blockIdx.x == 144) {
        for (int i = threadIdx.x; i < 16384; i += 256) {
            int k = i >> 8, n = i & 255;
            int addr = (n >> 4) * 1024 + (k >> 5) * 512 + ((k >> 3) & 3) * 128
                     + (n & 15) * 8 + (k & 7);
            Wupb[addr] = f2bf(Wup[k * 256 + n]);
        }
        return;
    }
    __shared__ float T[64][65];
    int bx = blockIdx.x % 12, by = blockIdx.x / 12;
    for (int i = threadIdx.x; i < 4096; i += 256) {
        int r = i >> 6, cc = i & 63;
        T[r][cc] = W[(size_t)(by * 64 + r) * HID + bx * 64 + cc];
    }
    __syncthreads();
    for (int i = threadIdx.x; i < 4096; i += 256) {
        int r = i >> 6, cc = i & 63;
        int n = bx * 64 + r, k = by * 64 + cc;
        Wt[fragaddr(n, k)] = f2bf(T[cc][r]);
    }
}

// ---------------------------------------------------------------------------
// K1+K2 FUSED (r9 proven shape: grid 6144 = 96 bh x 64 qb, 32 q/block).
// r10 lesson: shrinking the grid to cut atomic traffic collapsed sustained
// BW (880 -> 522 GB/s) — TLP generates BW. This version keeps the r9 grid
// and replaces the atomicAdd RMW tail (~50 MB at RMW speed) with plain
// streaming stores of per-block partials into the DEAD lo-half of Qs;
// k_reduce sums them. Streaming stores run at cast-kernel speeds (>3 TB/s).
// ---------------------------------------------------------------------------
__global__ __launch_bounds__(512) void k_fused(const short* __restrict__ Qs,
                                               const short* __restrict__ Ks,
                                               float* __restrict__ Part) {
    __shared__ short Kt[2][4096];        // 16 KB: chunk = 64 s x 64 k fp16
    __shared__ float iacc[2][1024];      // 8 KB: per-qi block-local iattn
    __shared__ float Lred[2][4][16];     // cross-si L partials

    int bh = blockIdx.x >> 6, qb = blockIdx.x & 63;
    int tid = threadIdx.x;
    int w = tid >> 6, lane = tid & 63;
    int qi = w >> 2, si = w & 3;
    int quad = lane >> 4, c = lane & 15;

    // Q fragments (single-plane): group = bh*128 + qb*2 + qi
    const short* ap = Qs + ((size_t)bh * 128 + qb * 2 + qi) * 2048 + lane * 8;
    f16x8 a0 = ash(*(const bf16x8*)(ap));
    f16x8 a1 = ash(*(const bf16x8*)(ap + 512));

    const short* kbase = Ks + (size_t)bh * SS * 128;
    size_t soff = (size_t)(tid >> 7) * 2048 + (size_t)(tid & 127) * 8;

    f32x4 pt[16];
    bf16x8 st = *(const bf16x8*)(kbase + soff);

#pragma unroll
    for (int cc = 0; cc < 16; cc++) {
        int buf = cc & 1;
        *(bf16x8*)(&Kt[buf][tid * 8]) = st;
        if (cc + 1 < 16)
            st = *(const bf16x8*)(kbase + (size_t)(cc + 1) * 8192 + soff);
        __syncthreads();
        f16x8 kb0 = ash(*(const bf16x8*)(&Kt[buf][si * 1024 + lane * 8]));
        f16x8 kb1 = ash(*(const bf16x8*)(&Kt[buf][si * 1024 + 512 + lane * 8]));
        f32x4 acc = (f32x4){0.f, 0.f, 0.f, 0.f};
        acc = MFMA16H(a0, kb0, acc);
        acc = MFMA16H(a1, kb1, acc);
#pragma unroll
        for (int r = 0; r < 4; r++) pt[cc][r] = EXP2(acc[r]);
    }

    // ---- L_q = sum_s P: register sum over chunks, shfl over c, LDS over si
    float Lp[4], rl[4];
#pragma unroll
    for (int r = 0; r < 4; r++) {
        float v = 0.f;
#pragma unroll
        for (int cc = 0; cc < 16; cc++) v += pt[cc][r];
        v += __shfl_xor(v, 1);
        v += __shfl_xor(v, 2);
        v += __shfl_xor(v, 4);
        v += __shfl_xor(v, 8);
        Lp[r] = v;
    }
    if (c == 0) {
#pragma unroll
        for (int r = 0; r < 4; r++) Lred[qi][si][quad * 4 + r] = Lp[r];
    }
    __syncthreads();
#pragma unroll
    for (int r = 0; r < 4; r++)
        rl[r] = __builtin_amdgcn_rcpf(
            Lred[qi][0][quad * 4 + r] + Lred[qi][1][quad * 4 + r] +
            Lred[qi][2][quad * 4 + r] + Lred[qi][3][quad * 4 + r]);

    // ---- iattn contribution: sum_q P/L, reduce over quads, write-once iacc
#pragma unroll
    for (int cc = 0; cc < 16; cc++) {
        float v = pt[cc][0] * rl[0] + pt[cc][1] * rl[1]
                + pt[cc][2] * rl[2] + pt[cc][3] * rl[3];
        v += __shfl_xor(v, 16);
        v += __shfl_xor(v, 32);
        if (lane < 16) iacc[qi][cc * 64 + si * 16 + lane] = v;
    }
    __syncthreads();
    // streaming partial store (no RMW): Part[blk][i] in Qs lo-half space
    for (int i = tid; i < 1024; i += 512) {
        size_t j = (size_t)blockIdx.x * 1024 + i;
        Part[partaddr(j)] = iacc[0][i] + iacc[1][i];
    }
}

// ---------------------------------------------------------------------------
// K3: reduce 64 per-qb partials -> iattn[bh][s].  grid 384 = 96 bh x 4.
// Coalesced: 256 consecutive floats per (blk,qb) step. 24 MB read, 0.4 write.
// ---------------------------------------------------------------------------
__global__ __launch_bounds__(256) void k_reduce(const float* __restrict__ Part,
                                                float* __restrict__ iattn) {
    int bh = blockIdx.x >> 2, quarter = blockIdx.x & 3;
    int s = quarter * 256 + threadIdx.x;
    float v = 0.f;
#pragma unroll 8
    for (int qb = 0; qb < 64; qb++) {
        size_t j = ((size_t)(bh * 64 + qb)) * 1024 + s;
        v += Part[partaddr(j)];
    }
    iattn[(size_t)bh * SS + s] = v;
}

// ---------------------------------------------------------------------------
// K4: fused pool+argmax+region-gather+upsample GEMM + pixel-shuffle.
// Xb written in FRAGMENT order (A-operand of k_out).
// ---------------------------------------------------------------------------
__global__ __launch_bounds__(256, 2) void k_up(const float* __restrict__ img,
                                               const float* __restrict__ iattn,
                                               const short* __restrict__ Wupb,
                                               short* __restrict__ Xb) {
    __shared__ short Reg[16384];         // 32 KB, aliased for pool phase
    float* F = (float*)Reg;
    float* Apool = F;                    // [1024]
    float* Vp = F + 1024;                // [544]
    float* bvp = F + 1568;               // [256]
    int*   bip = (int*)(F + 1824);       // [256]

    int bh = blockIdx.x >> 2, nq = blockIdx.x & 3;
    int b = bh / NH, h = bh - b * NH;
    int tid = threadIdx.x;
    int w = tid >> 6, lane = tid & 63;
    int quad = lane >> 4, c = lane & 15;

    // ---- pool + argmax (np first-max tiebreak) ----
    for (int i = tid; i < 1024; i += 256) Apool[i] = iattn[(size_t)bh * SS + i];
    __syncthreads();
    for (int i = tid; i < POOLED * EDGE; i += 256) {
        int r = i >> 5, cc = i & 31;
        float s = 0.f;
#pragma unroll
        for (int k = 0; k < KPOOL; k++) s += Apool[(r + k) * EDGE + cc];
        Vp[i] = s;
    }
    __syncthreads();
    float best = -1e30f;
    int bidx = 1 << 30;
    for (int i = tid; i < POOLED * POOLED; i += 256) {
        int r = i / POOLED, cc = i - r * POOLED;
        float s = 0.f;
#pragma unroll
        for (int k = 0; k < KPOOL; k++) s += Vp[r * EDGE + cc + k];
        if (s > best || (s == best && i < bidx)) { best = s; bidx = i; }
    }
    bvp[tid] = best;
    bip[tid] = bidx;
    __syncthreads();
    for (int off = 128; off; off >>= 1) {
        if (tid < off) {
            float ov = bvp[tid + off];
            int oi = bip[tid + off];
            if (ov > bvp[tid] || (ov == bvp[tid] && oi < bip[tid])) {
                bvp[tid] = ov;
                bip[tid] = oi;
            }
        }
        __syncthreads();
    }
    int widx = bip[0];
    __syncthreads();                     // all reads done before staging overwrites
    int r0 = widx / POOLED, c0 = widx - r0 * POOLED;

    // ---- stage region bf16 in A-fragment order ----
    for (int p = tid; p < 2048; p += 256) {
        int pos = p >> 3, sub = p & 7;   // sub -> d = sub*8..sub*8+7
        int gi = r0 + (pos >> 4), gj = c0 + (pos & 15);
        const float* sp = img + ((size_t)b * SS + gi * EDGE + gj) * HID + h * DD + sub * 8;
        bf16x8 v;
#pragma unroll
        for (int j = 0; j < 8; j++) v[j] = f2bf(sp[j]);
        *(bf16x8*)(&Reg[(pos >> 4) * 1024 + (sub >> 2) * 512 + (sub & 3) * 128 + (pos & 15) * 8]) = v;
    }
    __syncthreads();

    // ---- B-fragments (this block's 64 oc = 4 n-tiles) ----
    bf16x8 bu[4][2];
#pragma unroll
    for (int u = 0; u < 4; u++) {
#pragma unroll
        for (int kh = 0; kh < 2; kh++)
            bu[u][kh] = *(const bf16x8*)(Wupb + (nq * 4 + u) * 1024 + kh * 512 + lane * 8);
    }

    // ---- MFMA + pixel-shuffle epilogue (fragment-order Xb writes) ----
#pragma unroll
    for (int t = 0; t < 4; t++) {
        int g = w * 4 + t;               // pos group [0,16)
        bf16x8 a0 = *(const bf16x8*)(&Reg[g * 1024 + lane * 8]);
        bf16x8 a1 = *(const bf16x8*)(&Reg[g * 1024 + 512 + lane * 8]);
#pragma unroll
        for (int u = 0; u < 4; u++) {
            f32x4 acc = (f32x4){0.f, 0.f, 0.f, 0.f};
            acc = MFMA16B(a0, bu[u][0], acc);
            acc = MFMA16B(a1, bu[u][1], acc);
#pragma unroll
            for (int r = 0; r < 4; r++) {
                int pos = g * 16 + quad * 4 + r;
                int oc = nq * 64 + u * 16 + c;
                int i16 = pos >> 4, j16 = pos & 15;
                int a = oc >> 7, bbit = (oc >> 6) & 1, dp = oc & 63;
                int p2 = (2 * i16 + a) * EDGE + (2 * j16 + bbit);
                int row = b * SS + p2, kdim = h * DD + dp;
                Xb[fragaddr(row, kdim)] = f2bf(acc[r]);
            }
        }
    }
}

// ---------------------------------------------------------------------------
// K5: out = img + gelu(X @ W_in)   (bf16 MFMA, M=8192 N=768 K=768)
// LDS-staged from fragment-order Xb/Wt (proven r8 structure).
// ---------------------------------------------------------------------------
__global__ __launch_bounds__(256) void k_out(const short* __restrict__ Xb,
                                             const short* __restrict__ Wt,
                                             const float* __restrict__ img,
                                             float* __restrict__ out) {
    __shared__ short At[2][4096];        // 128 rows x 32 k, frag order (16 KB)
    __shared__ short Bt[2][2048];        // 64 rows x 32 k, frag order (8 KB)
    int mblk = blockIdx.x & 63, nblk = blockIdx.x >> 6;
    int tid = threadIdx.x;
    int w = tid >> 6, lane = tid & 63;
    int quad = lane >> 4, c = lane & 15;
    int gm0 = mblk * 8, gn0 = nblk * 4;  // 16-row group bases
    int m0 = mblk * 128, n0 = nblk * 64;

    // staging sources (unit = 16B): A units tid and tid+256, B unit tid
    int ua1 = tid + 256;
    const short* srcA0 = Xb + ((size_t)(gm0 + (tid >> 6)) * 24) * 512 + (tid & 63) * 8;
    const short* srcA1 = Xb + ((size_t)(gm0 + (ua1 >> 6)) * 24) * 512 + (ua1 & 63) * 8;
    const short* srcB  = Wt + ((size_t)(gn0 + (tid >> 6)) * 24) * 512 + (tid & 63) * 8;

    f32x4 acc[2][4];
#pragma unroll
    for (int t = 0; t < 2; t++)
#pragma unroll
        for (int u = 0; u < 4; u++) acc[t][u] = (f32x4){0.f, 0.f, 0.f, 0.f};

    bf16x8 sa0 = *(const bf16x8*)(srcA0);
    bf16x8 sa1 = *(const bf16x8*)(srcA1);
    bf16x8 sb  = *(const bf16x8*)(srcB);

    for (int kk = 0; kk < 24; kk++) {
        int buf = kk & 1;
        *(bf16x8*)(&At[buf][tid * 8]) = sa0;
        *(bf16x8*)(&At[buf][ua1 * 8]) = sa1;
        *(bf16x8*)(&Bt[buf][tid * 8]) = sb;
        if (kk + 1 < 24) {
            sa0 = *(const bf16x8*)(srcA0 + (kk + 1) * 512);
            sa1 = *(const bf16x8*)(srcA1 + (kk + 1) * 512);
            sb  = *(const bf16x8*)(srcB  + (kk + 1) * 512);
        }
        __syncthreads();
        bf16x8 a0 = *(const bf16x8*)(&At[buf][(2 * w + 0) * 512 + lane * 8]);
        bf16x8 a1 = *(const bf16x8*)(&At[buf][(2 * w + 1) * 512 + lane * 8]);
        bf16x8 b0 = *(const bf16x8*)(&Bt[buf][0 * 512 + lane * 8]);
        bf16x8 b1 = *(const bf16x8*)(&Bt[buf][1 * 512 + lane * 8]);
        bf16x8 b2 = *(const bf16x8*)(&Bt[buf][2 * 512 + lane * 8]);
        bf16x8 b3 = *(const bf16x8*)(&Bt[buf][3 * 512 + lane * 8]);
        acc[0][0] = MFMA16B(a0, b0, acc[0][0]);
        acc[0][1] = MFMA16B(a0, b1, acc[0][1]);
        acc[0][2] = MFMA16B(a0, b2, acc[0][2]);
        acc[0][3] = MFMA16B(a0, b3, acc[0][3]);
        acc[1][0] = MFMA16B(a1, b0, acc[1][0]);
        acc[1][1] = MFMA16B(a1, b1, acc[1][1]);
        acc[1][2] = MFMA16B(a1, b2, acc[1][2]);
        acc[1][3] = MFMA16B(a1, b3, acc[1][3]);
    }

#pragma unroll
    for (int t = 0; t < 2; t++) {
#pragma unroll
        for (int u = 0; u < 4; u++) {
#pragma unroll
            for (int r = 0; r < 4; r++) {
                int row = m0 + w * 32 + t * 16 + quad * 4 + r;
                int col = n0 + u * 16 + c;
                float x = acc[t][u][r];
                float g = 0.5f * x * (1.f + erff(x * 0.70710678118654752f));
                size_t o = (size_t)row * HID + col;
                out[o] = img[o] + g;
            }
        }
    }
}

// ---------------------------------------------------------------------------
// launch
// ---------------------------------------------------------------------------
extern "C" void kernel_launch(void* const* d_in, const int* in_sizes, int n_in,
                              void* d_out, int out_size, void* d_ws, size_t ws_size,
                              hipStream_t stream) {
    const float* img = (const float*)d_in[0];   // [8,1024,768]
    const float* txt = (const float*)d_in[1];   // [8,2048,768]
    const float* Win = (const float*)d_in[2];   // [768,768]
    const float* Wup = (const float*)d_in[3];   // [64,256]
    float* out = (float*)d_out;

    char* w = (char*)d_ws;
    short* Qs    = (short*)(w);                         // 96*2048*128*2 = 50331648
    short* Ks    = (short*)(w + 50331648);              // 96*1024*128*2 = 25165824
    short* Wt    = (short*)(w + 75497472);              // 768*768*2     = 1179648
    float* iattn = (float*)(w + 77463552);              // 96*1024*4     = 393216
    short* Wupb  = (short*)(w + 77856768);              // 16384*2       = 32768
    float* Part  = (float*)(w);                         // partials in Qs lo-half
    short* Xb    = (short*)(w);                         // aliases Qs (dead after k_reduce)

    k_castq<<<dim3(6144), dim3(256), 0, stream>>>(txt, Qs);
    k_castk<<<dim3(3072), dim3(256), 0, stream>>>(img, Ks);
    k_castw<<<dim3(145), dim3(256), 0, stream>>>(Win, Wup, Wt, Wupb);
    k_fused<<<dim3(6144), dim3(512), 0, stream>>>(Qs, Ks, Part);
    k_reduce<<<dim3(384), dim3(256), 0, stream>>>(Part, iattn);
    k_up<<<dim3(384), dim3(256), 0, stream>>>(img, iattn, Wupb, Xb);
    k_out<<<dim3(768), dim3(256), 0, stream>>>(Xb, Wt, img, out);
}

// Round 12
// 261.398 us; speedup vs baseline: 1.1532x; 1.0176x over previous
//
#include <hip/hip_runtime.h>
#include <cstdint>
#include <cstddef>

// ---------------------------------------------------------------------------
// Problem constants
// ---------------------------------------------------------------------------
#define BB    8      // batch
#define NH    12     // heads
#define BH    96     // BB*NH
#define SS    1024   // image tokens (32x32)
#define QQ    2048   // text tokens
#define DD    64     // head dim
#define HID   768
#define EDGE  32
#define KPOOL 16
#define POOLED 17

typedef short bf16x8 __attribute__((ext_vector_type(8)));
typedef _Float16 f16x8 __attribute__((ext_vector_type(8)));
typedef float f32x4  __attribute__((ext_vector_type(4)));

#define MFMA16B(a, b, c) __builtin_amdgcn_mfma_f32_16x16x32_bf16((a), (b), (c), 0, 0, 0)
#define MFMA16H(a, b, c) __builtin_amdgcn_mfma_f32_16x16x32_f16((a), (b), (c), 0, 0, 0)

// scores in base-2: Q pre-scaled by log2(e)/8 so exp(s/8) == exp2(score2)
#define QSCALE 0.18033688011112042f

#if __has_builtin(__builtin_amdgcn_exp2f)
#define EXP2(x) __builtin_amdgcn_exp2f(x)
#else
#define EXP2(x) exp2f(x)
#endif

__device__ __forceinline__ short f2bf(float x) {
    unsigned u = __builtin_bit_cast(unsigned, x);
    u = u + 0x7fffu + ((u >> 16) & 1u);          // RNE
    return (short)(u >> 16);
}
__device__ __forceinline__ f16x8 ash(bf16x8 v) {
    return __builtin_bit_cast(f16x8, v);
}

// Fragment-order address for a [rows][K=768] bf16 matrix, 32-k chunks:
// addr(row,k) = ((row>>4)*24 + (k>>5))*512 + ((k>>3)&3)*128 + (row&15)*8 + (k&7)
__device__ __forceinline__ size_t fragaddr(int row, int k) {
    return ((size_t)(row >> 4) * 24 + (k >> 5)) * 512 + ((k >> 3) & 3) * 128
         + (row & 15) * 8 + (k & 7);
}

// Partials live in the DEAD lo-half of each Qs group (Q is single-plane):
// float j -> float-index (j>>9)*1024 + 512 + (j&511) in the float view of Qs.
__device__ __forceinline__ size_t partaddr(size_t j) {
    return (j >> 9) * 1024 + 512 + (j & 511);
}

// ---------------------------------------------------------------------------
// Fragment-order layout for Qs/Ks:
//   rows grouped by 16 (group g, row-in-group c). Per group: 2048 shorts =
//   4 chunks of 512: ch0=hi,k[0:32) ch1=hi,k[32:64) (ch2/ch3 = partials space)
//   chunk internal: [quad(4)][c(16)][j(8)]  -> frag read = base + lane*8 shorts
// Both Q and K: fp16 hi plane ONLY (single-plane scores; noise ~6e-4, 8x
// below the r1 bf16 failure point; P and L share identical scores so the
// softmax normalization is exact under the perturbation).
// ---------------------------------------------------------------------------

// K0a: cast text -> Qs fragment-order (scaled by QSCALE), fp16 hi plane only
__global__ __launch_bounds__(256) void k_castq(const float* __restrict__ txt,
                                               short* __restrict__ Qs) {
    int i = blockIdx.x * 256 + threadIdx.x;
    int quad = i & 3, kh = (i >> 2) & 1;
    int row = i >> 3;                    // bh*2048 + q
    int c = row & 15, g = row >> 4;
    int q = row & 2047, bh = row >> 11;
    int b = bh / NH, h = bh - b * NH;
    const float* sp = txt + ((size_t)b * QQ + q) * HID + h * DD + kh * 32 + quad * 8;
    bf16x8 vh;
#pragma unroll
    for (int j = 0; j < 8; j++) {
        _Float16 hi = (_Float16)(sp[j] * QSCALE);
        vh[j] = __builtin_bit_cast(short, hi);
    }
    *(bf16x8*)(Qs + (size_t)g * 2048 + kh * 512 + quad * 128 + c * 8) = vh;
}

// K0b: cast image -> Ks fragment-order (unscaled), fp16 hi plane ONLY
__global__ __launch_bounds__(256) void k_castk(const float* __restrict__ img,
                                               short* __restrict__ Ks) {
    int i = blockIdx.x * 256 + threadIdx.x;
    int quad = i & 3, kh = (i >> 2) & 1;
    int row = i >> 3;                    // bh*1024 + s
    int c = row & 15, g = row >> 4;
    int s = row & 1023, bh = row >> 10;
    int b = bh / NH, h = bh - b * NH;
    const float* sp = img + ((size_t)b * SS + s) * HID + h * DD + kh * 32 + quad * 8;
    bf16x8 vh;
#pragma unroll
    for (int j = 0; j < 8; j++) {
        _Float16 hi = (_Float16)sp[j];
        vh[j] = __builtin_bit_cast(short, hi);
    }
    *(bf16x8*)(Ks + (size_t)g * 2048 + kh * 512 + quad * 128 + c * 8) = vh;
}

// K0c: blocks 0..143: W_in [k][n] -> bf16 Wt in FRAGMENT order [n-row][k].
//      block 144: W_up [64][256] -> bf16 B-fragment order Wupb.
__global__ __launch_bounds__(256) void k_castw(const float* __restrict__ W,
                                               const float* __restrict__ Wup,
                                               short* __restrict__ Wt,
                                               short* __restrict__ Wupb) {
    if (blockIdx.x == 144) {
        for (int i = threadIdx.x; i < 16384; i += 256) {
            int k = i >> 8, n = i & 255;
            int addr = (n >> 4) * 1024 + (k >> 5) * 512 + ((k >> 3) & 3) * 128
                     + (n & 15) * 8 + (k & 7);
            Wupb[addr] = f2bf(Wup[k * 256 + n]);
        }
        return;
    }
    __shared__ float T[64][65];
    int bx = blockIdx.x % 12, by = blockIdx.x / 12;
    for (int i = threadIdx.x; i < 4096; i += 256) {
        int r = i >> 6, cc = i & 63;
        T[r][cc] = W[(size_t)(by * 64 + r) * HID + bx * 64 + cc];
    }
    __syncthreads();
    for (int i = threadIdx.x; i < 4096; i += 256) {
        int r = i >> 6, cc = i & 63;
        int n = bx * 64 + r, k = by * 64 + cc;
        Wt[fragaddr(n, k)] = f2bf(T[cc][r]);
    }
}

// ---------------------------------------------------------------------------
// K1+K2 FUSED.  grid 6144; 32 q/block (r9/r11 proven shape).
// r11 lesson: FETCH 61.5 MB unchanged after atomic removal => the excess is
// K L2 replication across XCDs (bh = blockIdx>>6 scatters a bh's 64 blocks
// round-robin over 8 XCDs).  Fix 1: XCD swizzle — bh = (m>>9)*8 + (m&7) so
// all 64 q-blocks of a bh share m%8 (one XCD) -> K fetched ~once (36->13MB).
// Fix 2: 128-s chunks (8 barriers instead of 16; 2x compute per barrier to
// hide the vmcnt-drain).  Same MFMA/exp2 counts; partials use LOGICAL
// (bh,qb) so k_reduce is unchanged.
// ---------------------------------------------------------------------------
__global__ __launch_bounds__(512) void k_fused(const short* __restrict__ Qs,
                                               const short* __restrict__ Ks,
                                               float* __restrict__ Part) {
    __shared__ short Kt[2][8192];        // 32 KB: chunk = 128 s x 64 k fp16
    __shared__ float iacc[2][1024];      // 8 KB: per-qi block-local iattn
    __shared__ float Lred[2][4][16];     // cross-si L partials

    int m = blockIdx.x;
    int bh = ((m >> 9) << 3) | (m & 7);  // 12 bh-groups x 8 XCD slots
    int qb = (m >> 3) & 63;
    int tid = threadIdx.x;
    int w = tid >> 6, lane = tid & 63;
    int qi = w >> 2, si = w & 3;
    int quad = lane >> 4, c = lane & 15;

    // Q fragments (single-plane): group = bh*128 + qb*2 + qi
    const short* ap = Qs + ((size_t)bh * 128 + qb * 2 + qi) * 2048 + lane * 8;
    f16x8 a0 = ash(*(const bf16x8*)(ap));
    f16x8 a1 = ash(*(const bf16x8*)(ap + 512));

    const short* kbase = Ks + (size_t)bh * SS * 128;
    // staging: chunk = 8 groups x 1024 hi-shorts; 1024 units of 8 shorts,
    // unit idx: group = idx>>7, off = idx&127. Thread covers idx=tid, tid+512.
    size_t s0 = (size_t)(tid >> 7) * 2048 + (size_t)(tid & 127) * 8;
    int i1 = tid + 512;
    size_t s1 = (size_t)(i1 >> 7) * 2048 + (size_t)(i1 & 127) * 8;

    f32x4 pt[16];
    bf16x8 st0 = *(const bf16x8*)(kbase + s0);
    bf16x8 st1 = *(const bf16x8*)(kbase + s1);

#pragma unroll
    for (int cc = 0; cc < 8; cc++) {
        int buf = cc & 1;
        *(bf16x8*)(&Kt[buf][tid * 8]) = st0;
        *(bf16x8*)(&Kt[buf][(tid + 512) * 8]) = st1;
        if (cc + 1 < 8) {
            st0 = *(const bf16x8*)(kbase + (size_t)(cc + 1) * 16384 + s0);
            st1 = *(const bf16x8*)(kbase + (size_t)(cc + 1) * 16384 + s1);
        }
        __syncthreads();
#pragma unroll
        for (int h = 0; h < 2; h++) {
            const short* kp = &Kt[buf][(si + h * 4) * 1024 + lane * 8];
            f16x8 kb0 = ash(*(const bf16x8*)(kp));
            f16x8 kb1 = ash(*(const bf16x8*)(kp + 512));
            f32x4 acc = (f32x4){0.f, 0.f, 0.f, 0.f};
            acc = MFMA16H(a0, kb0, acc);
            acc = MFMA16H(a1, kb1, acc);
#pragma unroll
            for (int r = 0; r < 4; r++) pt[cc * 2 + h][r] = EXP2(acc[r]);
        }
    }

    // ---- L_q = sum_s P: register sum over chunks, shfl over c, LDS over si
    float rl[4];
#pragma unroll
    for (int r = 0; r < 4; r++) {
        float v = 0.f;
#pragma unroll
        for (int cc = 0; cc < 16; cc++) v += pt[cc][r];
        v += __shfl_xor(v, 1);
        v += __shfl_xor(v, 2);
        v += __shfl_xor(v, 4);
        v += __shfl_xor(v, 8);
        if (c == 0) Lred[qi][si][quad * 4 + r] = v;
    }
    __syncthreads();
#pragma unroll
    for (int r = 0; r < 4; r++)
        rl[r] = __builtin_amdgcn_rcpf(
            Lred[qi][0][quad * 4 + r] + Lred[qi][1][quad * 4 + r] +
            Lred[qi][2][quad * 4 + r] + Lred[qi][3][quad * 4 + r]);

    // ---- iattn contribution: sum_q P/L, reduce over quads, write-once iacc
#pragma unroll
    for (int cc = 0; cc < 8; cc++) {
#pragma unroll
        for (int h = 0; h < 2; h++) {
            float v = pt[cc * 2 + h][0] * rl[0] + pt[cc * 2 + h][1] * rl[1]
                    + pt[cc * 2 + h][2] * rl[2] + pt[cc * 2 + h][3] * rl[3];
            v += __shfl_xor(v, 16);
            v += __shfl_xor(v, 32);
            if (lane < 16) iacc[qi][cc * 128 + (si + h * 4) * 16 + lane] = v;
        }
    }
    __syncthreads();
    // streaming partial store (no RMW), indexed by LOGICAL (bh,qb)
    for (int i = tid; i < 1024; i += 512) {
        size_t j = ((size_t)(bh * 64 + qb)) * 1024 + i;
        Part[partaddr(j)] = iacc[0][i] + iacc[1][i];
    }
}

// ---------------------------------------------------------------------------
// K3: reduce 64 per-qb partials -> iattn[bh][s].  grid 384 = 96 bh x 4.
// Coalesced: 256 consecutive floats per (blk,qb) step. 24 MB read, 0.4 write.
// ---------------------------------------------------------------------------
__global__ __launch_bounds__(256) void k_reduce(const float* __restrict__ Part,
                                                float* __restrict__ iattn) {
    int bh = blockIdx.x >> 2, quarter = blockIdx.x & 3;
    int s = quarter * 256 + threadIdx.x;
    float v = 0.f;
#pragma unroll 8
    for (int qb = 0; qb < 64; qb++) {
        size_t j = ((size_t)(bh * 64 + qb)) * 1024 + s;
        v += Part[partaddr(j)];
    }
    iattn[(size_t)bh * SS + s] = v;
}

// ---------------------------------------------------------------------------
// K4: fused pool+argmax+region-gather+upsample GEMM + pixel-shuffle.
// Xb written in FRAGMENT order (A-operand of k_out).
// ---------------------------------------------------------------------------
__global__ __launch_bounds__(256, 2) void k_up(const float* __restrict__ img,
                                               const float* __restrict__ iattn,
                                               const short* __restrict__ Wupb,
                                               short* __restrict__ Xb) {
    __shared__ short Reg[16384];         // 32 KB, aliased for pool phase
    float* F = (float*)Reg;
    float* Apool = F;                    // [1024]
    float* Vp = F + 1024;                // [544]
    float* bvp = F + 1568;               // [256]
    int*   bip = (int*)(F + 1824);       // [256]

    int bh = blockIdx.x >> 2, nq = blockIdx.x & 3;
    int b = bh / NH, h = bh - b * NH;
    int tid = threadIdx.x;
    int w = tid >> 6, lane = tid & 63;
    int quad = lane >> 4, c = lane & 15;

    // ---- pool + argmax (np first-max tiebreak) ----
    for (int i = tid; i < 1024; i += 256) Apool[i] = iattn[(size_t)bh * SS + i];
    __syncthreads();
    for (int i = tid; i < POOLED * EDGE; i += 256) {
        int r = i >> 5, cc = i & 31;
        float s = 0.f;
#pragma unroll
        for (int k = 0; k < KPOOL; k++) s += Apool[(r + k) * EDGE + cc];
        Vp[i] = s;
    }
    __syncthreads();
    float best = -1e30f;
    int bidx = 1 << 30;
    for (int i = tid; i < POOLED * POOLED; i += 256) {
        int r = i / POOLED, cc = i - r * POOLED;
        float s = 0.f;
#pragma unroll
        for (int k = 0; k < KPOOL; k++) s += Vp[r * EDGE + cc + k];
        if (s > best || (s == best && i < bidx)) { best = s; bidx = i; }
    }
    bvp[tid] = best;
    bip[tid] = bidx;
    __syncthreads();
    for (int off = 128; off; off >>= 1) {
        if (tid < off) {
            float ov = bvp[tid + off];
            int oi = bip[tid + off];
            if (ov > bvp[tid] || (ov == bvp[tid] && oi < bip[tid])) {
                bvp[tid] = ov;
                bip[tid] = oi;
            }
        }
        __syncthreads();
    }
    int widx = bip[0];
    __syncthreads();                     // all reads done before staging overwrites
    int r0 = widx / POOLED, c0 = widx - r0 * POOLED;

    // ---- stage region bf16 in A-fragment order ----
    for (int p = tid; p < 2048; p += 256) {
        int pos = p >> 3, sub = p & 7;   // sub -> d = sub*8..sub*8+7
        int gi = r0 + (pos >> 4), gj = c0 + (pos & 15);
        const float* sp = img + ((size_t)b * SS + gi * EDGE + gj) * HID + h * DD + sub * 8;
        bf16x8 v;
#pragma unroll
        for (int j = 0; j < 8; j++) v[j] = f2bf(sp[j]);
        *(bf16x8*)(&Reg[(pos >> 4) * 1024 + (sub >> 2) * 512 + (sub & 3) * 128 + (pos & 15) * 8]) = v;
    }
    __syncthreads();

    // ---- B-fragments (this block's 64 oc = 4 n-tiles) ----
    bf16x8 bu[4][2];
#pragma unroll
    for (int u = 0; u < 4; u++) {
#pragma unroll
        for (int kh = 0; kh < 2; kh++)
            bu[u][kh] = *(const bf16x8*)(Wupb + (nq * 4 + u) * 1024 + kh * 512 + lane * 8);
    }

    // ---- MFMA + pixel-shuffle epilogue (fragment-order Xb writes) ----
#pragma unroll
    for (int t = 0; t < 4; t++) {
        int g = w * 4 + t;               // pos group [0,16)
        bf16x8 a0 = *(const bf16x8*)(&Reg[g * 1024 + lane * 8]);
        bf16x8 a1 = *(const bf16x8*)(&Reg[g * 1024 + 512 + lane * 8]);
#pragma unroll
        for (int u = 0; u < 4; u++) {
            f32x4 acc = (f32x4){0.f, 0.f, 0.f, 0.f};
            acc = MFMA16B(a0, bu[u][0], acc);
            acc = MFMA16B(a1, bu[u][1], acc);
#pragma unroll
            for (int r = 0; r < 4; r++) {
                int pos = g * 16 + quad * 4 + r;
                int oc = nq * 64 + u * 16 + c;
                int i16 = pos >> 4, j16 = pos & 15;
                int a = oc >> 7, bbit = (oc >> 6) & 1, dp = oc & 63;
                int p2 = (2 * i16 + a) * EDGE + (2 * j16 + bbit);
                int row = b * SS + p2, kdim = h * DD + dp;
                Xb[fragaddr(row, kdim)] = f2bf(acc[r]);
            }
        }
    }
}

// ---------------------------------------------------------------------------
// K5: out = img + gelu(X @ W_in)   (bf16 MFMA, M=8192 N=768 K=768)
// LDS-staged from fragment-order Xb/Wt (proven r8 structure).
// ---------------------------------------------------------------------------
__global__ __launch_bounds__(256) void k_out(const short* __restrict__ Xb,
                                             const short* __restrict__ Wt,
                                             const float* __restrict__ img,
                                             float* __restrict__ out) {
    __shared__ short At[2][4096];        // 128 rows x 32 k, frag order (16 KB)
    __shared__ short Bt[2][2048];        // 64 rows x 32 k, frag order (8 KB)
    int mblk = blockIdx.x & 63, nblk = blockIdx.x >> 6;
    int tid = threadIdx.x;
    int w = tid >> 6, lane = tid & 63;
    int quad = lane >> 4, c = lane & 15;
    int gm0 = mblk * 8, gn0 = nblk * 4;  // 16-row group bases
    int m0 = mblk * 128, n0 = nblk * 64;

    // staging sources (unit = 16B): A units tid and tid+256, B unit tid
    int ua1 = tid + 256;
    const short* srcA0 = Xb + ((size_t)(gm0 + (tid >> 6)) * 24) * 512 + (tid & 63) * 8;
    const short* srcA1 = Xb + ((size_t)(gm0 + (ua1 >> 6)) * 24) * 512 + (ua1 & 63) * 8;
    const short* srcB  = Wt + ((size_t)(gn0 + (tid >> 6)) * 24) * 512 + (tid & 63) * 8;

    f32x4 acc[2][4];
#pragma unroll
    for (int t = 0; t < 2; t++)
#pragma unroll
        for (int u = 0; u < 4; u++) acc[t][u] = (f32x4){0.f, 0.f, 0.f, 0.f};

    bf16x8 sa0 = *(const bf16x8*)(srcA0);
    bf16x8 sa1 = *(const bf16x8*)(srcA1);
    bf16x8 sb  = *(const bf16x8*)(srcB);

    for (int kk = 0; kk < 24; kk++) {
        int buf = kk & 1;
        *(bf16x8*)(&At[buf][tid * 8]) = sa0;
        *(bf16x8*)(&At[buf][ua1 * 8]) = sa1;
        *(bf16x8*)(&Bt[buf][tid * 8]) = sb;
        if (kk + 1 < 24) {
            sa0 = *(const bf16x8*)(srcA0 + (kk + 1) * 512);
            sa1 = *(const bf16x8*)(srcA1 + (kk + 1) * 512);
            sb  = *(const bf16x8*)(srcB  + (kk + 1) * 512);
        }
        __syncthreads();
        bf16x8 a0 = *(const bf16x8*)(&At[buf][(2 * w + 0) * 512 + lane * 8]);
        bf16x8 a1 = *(const bf16x8*)(&At[buf][(2 * w + 1) * 512 + lane * 8]);
        bf16x8 b0 = *(const bf16x8*)(&Bt[buf][0 * 512 + lane * 8]);
        bf16x8 b1 = *(const bf16x8*)(&Bt[buf][1 * 512 + lane * 8]);
        bf16x8 b2 = *(const bf16x8*)(&Bt[buf][2 * 512 + lane * 8]);
        bf16x8 b3 = *(const bf16x8*)(&Bt[buf][3 * 512 + lane * 8]);
        acc[0][0] = MFMA16B(a0, b0, acc[0][0]);
        acc[0][1] = MFMA16B(a0, b1, acc[0][1]);
        acc[0][2] = MFMA16B(a0, b2, acc[0][2]);
        acc[0][3] = MFMA16B(a0, b3, acc[0][3]);
        acc[1][0] = MFMA16B(a1, b0, acc[1][0]);
        acc[1][1] = MFMA16B(a1, b1, acc[1][1]);
        acc[1][2] = MFMA16B(a1, b2, acc[1][2]);
        acc[1][3] = MFMA16B(a1, b3, acc[1][3]);
    }

#pragma unroll
    for (int t = 0; t < 2; t++) {
#pragma unroll
        for (int u = 0; u < 4; u++) {
#pragma unroll
            for (int r = 0; r < 4; r++) {
                int row = m0 + w * 32 + t * 16 + quad * 4 + r;
                int col = n0 + u * 16 + c;
                float x = acc[t][u][r];
                float g = 0.5f * x * (1.f + erff(x * 0.70710678118654752f));
                size_t o = (size_t)row * HID + col;
                out[o] = img[o] + g;
            }
        }
    }
}

// ---------------------------------------------------------------------------
// launch
// ---------------------------------------------------------------------------
extern "C" void kernel_launch(void* const* d_in, const int* in_sizes, int n_in,
                              void* d_out, int out_size, void* d_ws, size_t ws_size,
                              hipStream_t stream) {
    const float* img = (const float*)d_in[0];   // [8,1024,768]
    const float* txt = (const float*)d_in[1];   // [8,2048,768]
    const float* Win = (const float*)d_in[2];   // [768,768]
    const float* Wup = (const float*)d_in[3];   // [64,256]
    float* out = (float*)d_out;

    char* w = (char*)d_ws;
    short* Qs    = (short*)(w);                         // 96*2048*128*2 = 50331648
    short* Ks    = (short*)(w + 50331648);              // 96*1024*128*2 = 25165824
    short* Wt    = (short*)(w + 75497472);              // 768*768*2     = 1179648
    float* iattn = (float*)(w + 77463552);              // 96*1024*4     = 393216
    short* Wupb  = (short*)(w + 77856768);              // 16384*2       = 32768
    float* Part  = (float*)(w);                         // partials in Qs lo-half
    short* Xb    = (short*)(w);                         // aliases Qs (dead after k_reduce)

    k_castq<<<dim3(6144), dim3(256), 0, stream>>>(txt, Qs);
    k_castk<<<dim3(3072), dim3(256), 0, stream>>>(img, Ks);
    k_castw<<<dim3(145), dim3(256), 0, stream>>>(Win, Wup, Wt, Wupb);
    k_fused<<<dim3(6144), dim3(512), 0, stream>>>(Qs, Ks, Part);
    k_reduce<<<dim3(384), dim3(256), 0, stream>>>(Part, iattn);
    k_up<<<dim3(384), dim3(256), 0, stream>>>(img, iattn, Wupb, Xb);
    k_out<<<dim3(768), dim3(256), 0, stream>>>(Xb, Wt, img, out);
}